// Round 6
// baseline (486.343 us; speedup 1.0000x reference)
//
#include <hip/hip_runtime.h>
#include <hip/hip_bf16.h>

#define B 8
#define L 2048
#define D 1024

typedef __bf16 bf16x8 __attribute__((ext_vector_type(8)));
typedef __bf16 bf16x4 __attribute__((ext_vector_type(4)));
typedef float f32x4 __attribute__((ext_vector_type(4)));
typedef int i32x4 __attribute__((ext_vector_type(4)));

typedef __attribute__((address_space(3))) char lds_char;
typedef const __attribute__((address_space(1))) char glob_char;

// ===========================================================================
// Round 6: gemm 2-phase interleave (T3 fine-split on the proven 4-slot ring).
// pt_kernel / row_kernel identical to round 5 (single-variable round).
// Decomposition: dur = F(~312us fills) + K(~160us): pt ~20, row ~55, gemm ~65.
// ===========================================================================

// ---------------------------------------------------------------------------
// K1+K2 merged: blocks [0, 2048) = proj, blocks [2048, 18432) = transpose.
// ---------------------------------------------------------------------------
__global__ __launch_bounds__(256) void pt_kernel(const float* __restrict__ k,
                                                 const float* __restrict__ W2,
                                                 const float* __restrict__ b2,
                                                 float* __restrict__ e,
                                                 const float* __restrict__ v,
                                                 __bf16* __restrict__ vT) {
    __shared__ float tile[32][33];
    int blk = blockIdx.x;
    int t = threadIdx.x;
    if (blk < B * L / 4) {
        // ---- proj ----
        int wave = t >> 6, lane = t & 63;
        int row = blk * 4 + wave;      // 0 .. B*L-1
        const float4* k4 = (const float4*)(k + (size_t)row * D);
        const float4* w4 = (const float4*)W2;
        float p = 0.f;
#pragma unroll
        for (int s = 0; s < 4; s++) {
            float4 a = k4[s * 64 + lane];
            float4 w = w4[s * 64 + lane];
            p += a.x * w.x + a.y * w.y + a.z * w.z + a.w * w.w;
        }
        for (int off = 32; off > 0; off >>= 1)
            p += __shfl_down(p, off, 64);
        if (lane == 0) e[row] = __expf(p + b2[0]);
    } else {
        // ---- transpose ----
        int tb = blk - B * L / 4;      // 0..16383
        int b = tb >> 11;              // 2048 tiles per batch (64 j x 32 d)
        int rem = tb & 2047;
        int j0 = (rem >> 5) * 32;
        int d0 = (rem & 31) * 32;
        int jl = t >> 3;               // 0..31
        int dl = (t & 7) * 4;          // 0,4,..,28
        float4 val = *(const float4*)(v + ((size_t)b * L + j0 + jl) * D + d0 + dl);
        tile[jl][dl + 0] = val.x;
        tile[jl][dl + 1] = val.y;
        tile[jl][dl + 2] = val.z;
        tile[jl][dl + 3] = val.w;
        __syncthreads();
        int dl2 = t >> 3;              // 0..31
        int jl2 = (t & 7) * 4;         // 0,4,..,28
        bf16x4 o;
        o[0] = (__bf16)tile[jl2 + 0][dl2];
        o[1] = (__bf16)tile[jl2 + 1][dl2];
        o[2] = (__bf16)tile[jl2 + 2][dl2];
        o[3] = (__bf16)tile[jl2 + 3][dl2];
        *(bf16x4*)(vT + ((size_t)b * D + d0 + dl2) * L + j0 + jl2) = o;
    }
}

// ---------------------------------------------------------------------------
// K3: per (b,i) row: w[j] = mask ? 0 : e[j]; Z = sum w; attn = w/Z (fp32),
//     P = bf16(w/Z).  Wave-per-row, butterfly reduce, nt mask/attn.
// ---------------------------------------------------------------------------
__global__ __launch_bounds__(256) void row_kernel(const int* __restrict__ mask,
                                                  const float* __restrict__ e,
                                                  float* __restrict__ attn,
                                                  __bf16* __restrict__ P) {
    int t = threadIdx.x;
    int wid = t >> 6, lane = t & 63;
    for (int grp = blockIdx.x; grp < B * L / 4; grp += 2048) {
        int bid = grp * 4 + wid;       // row id: b*L + i
        int b = bid >> 11;             // L = 2048
        const i32x4* m4 = (const i32x4*)(mask + (size_t)bid * L);
        const f32x4* e4 = (const f32x4*)(e + (size_t)b * L);
        f32x4 wv[8];
        float z = 0.f;
#pragma unroll
        for (int s = 0; s < 8; s++) {
            int idx = s * 64 + lane;
            i32x4 mm = __builtin_nontemporal_load(&m4[idx]);
            f32x4 ee = e4[idx];
            f32x4 ww;
            ww.x = mm.x ? 0.f : ee.x;
            ww.y = mm.y ? 0.f : ee.y;
            ww.z = mm.z ? 0.f : ee.z;
            ww.w = mm.w ? 0.f : ee.w;
            wv[s] = ww;
            z += ww.x + ww.y + ww.z + ww.w;
        }
#pragma unroll
        for (int off = 32; off > 0; off >>= 1)
            z += __shfl_xor(z, off, 64);
        float invZ = 1.f / z;          // every lane holds Z after butterfly
        f32x4* a4 = (f32x4*)(attn + (size_t)bid * L);
        __bf16* prow = P + (size_t)bid * L;
#pragma unroll
        for (int s = 0; s < 8; s++) {
            int idx = s * 64 + lane;
            f32x4 aa;
            aa.x = wv[s].x * invZ;
            aa.y = wv[s].y * invZ;
            aa.z = wv[s].z * invZ;
            aa.w = wv[s].w * invZ;
            __builtin_nontemporal_store(aa, &a4[idx]);
            bf16x4 pp;
            pp[0] = (__bf16)aa.x;
            pp[1] = (__bf16)aa.y;
            pp[2] = (__bf16)aa.z;
            pp[3] = (__bf16)aa.w;
            *(bf16x4*)(prow + idx * 4) = pp;
        }
    }
}

// ---------------------------------------------------------------------------
// K4: out[b] = P[b] @ vT[b]^T (bf16 MFMA).
// Round-6: 2-phase fine interleave on the proven 4-slot BK=32 ring.
//   P1 = { stage-half-A(t+2) | vmcnt(6) | barrier | af[0..3]+bfr[0..3] | 16 MFMA }
//   P2 = { stage-half-B(t+2) | af[4..7] | 16 MFMA } | barrier
// vmcnt: outstanding at P1 wait = tile t(4) + t+1(4) + halfA(2) = 10;
// vmcnt(6) retires exactly tile t's 4 loads.  All indexing/swizzle/slots
// byte-identical to round 2-5 (numerics unchanged); only the schedule moved.
// Race safety: slot written by any STAGE_H is >=2 collective barriers past
// its last reader (waves at most one barrier apart).
// ---------------------------------------------------------------------------
#define BM 256
#define BN 256
#define BK 32
#define NT (L / BK)   // 64 K-tiles

__global__ __launch_bounds__(512, 2) void gemm_kernel(const __bf16* __restrict__ P,
                                                      const __bf16* __restrict__ vT,
                                                      float* __restrict__ out) {
    __shared__ __bf16 As[4][BM][BK];   // 64 KB
    __shared__ __bf16 Bs[4][BN][BK];   // 64 KB

    int p = blockIdx.x;             // 0..255
    int b = p & 7;                  // XCD id == batch
    int q = p >> 3;                 // 0..31 within XCD
    int i0 = (q & 7) * BM;          // 8 M-tiles
    int d0 = (q >> 3) * BN;         // 4 N-tiles

    int t = threadIdx.x;
    int wave = t >> 6, lane = t & 63;
    int wm = wave >> 2;             // 0..1  (M half)
    int wn = wave & 3;              // 0..3  (N quarter)
    const __bf16* Ab = P + ((size_t)b * L + i0) * L;    // row stride L (K dim)
    const __bf16* Bb = vT + ((size_t)b * D + d0) * L;   // row stride L (K dim)

    f32x4 acc[8][4];
#pragma unroll
    for (int ti = 0; ti < 8; ti++)
#pragma unroll
        for (int tj = 0; tj < 4; tj++)
            acc[ti][tj] = (f32x4){0.f, 0.f, 0.f, 0.f};

    int lrow = lane & 15;
    int kq = lane >> 4;             // 16B slot (0..3) of the 64B row

    bf16x8 af[4], bfr[4];

    // one half-tile of staging: 1 A-chunk + 1 B-chunk per thread (2 vm ops)
#define STAGE_H(tt, sh) do {                                                   \
        int k0_ = (tt) * BK; int sl_ = (tt) & 3;                               \
        int cbase_ = (sh) * 512 + wave * 64;                                   \
        int c_ = cbase_ + lane;                                                \
        int r_ = c_ >> 2;                                                      \
        int off_ = ((c_ ^ (r_ >> 1)) & 3) * 8;                                 \
        __builtin_amdgcn_global_load_lds(                                      \
            (glob_char*)(Ab + (size_t)r_ * L + k0_ + off_),                    \
            (lds_char*)((char*)&As[sl_][0][0] + cbase_ * 16), 16, 0, 0);       \
        __builtin_amdgcn_global_load_lds(                                      \
            (glob_char*)(Bb + (size_t)r_ * L + k0_ + off_),                    \
            (lds_char*)((char*)&Bs[sl_][0][0] + cbase_ * 16), 16, 0, 0);       \
    } while (0)

#define PHASE1(tt) do {                                                        \
        int sl_ = (tt) & 3;                                                    \
        _Pragma("unroll")                                                      \
        for (int ti = 0; ti < 4; ti++) {                                       \
            int rowA_ = wm * 128 + ti * 16 + lrow;                             \
            af[ti] = *(const bf16x8*)((const char*)&As[sl_][0][0] +            \
                      rowA_ * 64 + (((kq ^ (rowA_ >> 1)) & 3) << 4));          \
        }                                                                      \
        _Pragma("unroll")                                                      \
        for (int tj = 0; tj < 4; tj++) {                                       \
            int rowB_ = wn * 64 + tj * 16 + lrow;                              \
            bfr[tj] = *(const bf16x8*)((const char*)&Bs[sl_][0][0] +           \
                      rowB_ * 64 + (((kq ^ (rowB_ >> 1)) & 3) << 4));          \
        }                                                                      \
        __builtin_amdgcn_s_setprio(1);                                         \
        _Pragma("unroll")                                                      \
        for (int tj = 0; tj < 4; tj++)                                         \
            _Pragma("unroll")                                                  \
            for (int ti = 0; ti < 4; ti++)                                     \
                acc[ti][tj] = __builtin_amdgcn_mfma_f32_16x16x32_bf16(         \
                    af[ti], bfr[tj], acc[ti][tj], 0, 0, 0);                    \
        __builtin_amdgcn_s_setprio(0);                                         \
    } while (0)

#define PHASE2(tt) do {                                                        \
        int sl_ = (tt) & 3;                                                    \
        _Pragma("unroll")                                                      \
        for (int ti = 0; ti < 4; ti++) {                                       \
            int rowA_ = wm * 128 + (ti + 4) * 16 + lrow;                       \
            af[ti] = *(const bf16x8*)((const char*)&As[sl_][0][0] +            \
                      rowA_ * 64 + (((kq ^ (rowA_ >> 1)) & 3) << 4));          \
        }                                                                      \
        __builtin_amdgcn_s_setprio(1);                                         \
        _Pragma("unroll")                                                      \
        for (int tj = 0; tj < 4; tj++)                                         \
            _Pragma("unroll")                                                  \
            for (int ti = 0; ti < 4; ti++)                                     \
                acc[ti + 4][tj] = __builtin_amdgcn_mfma_f32_16x16x32_bf16(     \
                    af[ti], bfr[tj], acc[ti + 4][tj], 0, 0, 0);                \
        __builtin_amdgcn_s_setprio(0);                                         \
    } while (0)

    STAGE_H(0, 0); STAGE_H(0, 1);
    STAGE_H(1, 0); STAGE_H(1, 1);
    for (int tt = 0; tt < NT - 2; tt++) {
        STAGE_H(tt + 2, 0);
        asm volatile("s_waitcnt vmcnt(6)" ::: "memory");  // tile tt landed
        __builtin_amdgcn_s_barrier();
        __builtin_amdgcn_sched_barrier(0);
        PHASE1(tt);
        STAGE_H(tt + 2, 1);
        PHASE2(tt);
        __builtin_amdgcn_s_barrier();
    }
    asm volatile("s_waitcnt vmcnt(4)" ::: "memory");      // tile NT-2 landed
    __builtin_amdgcn_s_barrier();
    __builtin_amdgcn_sched_barrier(0);
    PHASE1(NT - 2);
    PHASE2(NT - 2);
    __builtin_amdgcn_s_barrier();
    asm volatile("s_waitcnt vmcnt(0)" ::: "memory");      // tile NT-1 landed
    __builtin_amdgcn_s_barrier();
    __builtin_amdgcn_sched_barrier(0);
    PHASE1(NT - 1);
    PHASE2(NT - 1);

#undef STAGE_H
#undef PHASE1
#undef PHASE2

    int col = lane & 15;
    int rquad = (lane >> 4) * 4;
#pragma unroll
    for (int ti = 0; ti < 8; ti++) {
#pragma unroll
        for (int tj = 0; tj < 4; tj++) {
#pragma unroll
            for (int r = 0; r < 4; r++) {
                int row = i0 + wm * 128 + ti * 16 + rquad + r;
                int c2 = d0 + wn * 64 + tj * 16 + col;
                out[((size_t)b * L + row) * D + c2] = acc[ti][tj][r];
            }
        }
    }
}

// ---------------------------------------------------------------------------
extern "C" void kernel_launch(void* const* d_in, const int* in_sizes, int n_in,
                              void* d_out, int out_size, void* d_ws, size_t ws_size,
                              hipStream_t stream) {
    // inputs: q(0) k(1) v(2) attn_mask(3) W1(4) b1(5) W2(6) b2(7)
    const float* k = (const float*)d_in[1];
    const float* v = (const float*)d_in[2];
    const int* mask = (const int*)d_in[3];
    const float* W2 = (const float*)d_in[6];
    const float* b2 = (const float*)d_in[7];

    float* out = (float*)d_out;                     // [B,L,D]
    float* attn = out + (size_t)B * L * D;          // [B,L,L]

    // workspace carve
    char* wp = (char*)d_ws;
    float* e = (float*)wp;             wp += (size_t)B * L * 4;
    __bf16* vT = (__bf16*)wp;          wp += (size_t)B * D * L * 2;
    __bf16* P = (__bf16*)wp;           wp += (size_t)B * L * L * 2;

    pt_kernel<<<B * L / 4 + (B * L / 32) * (D / 32), 256, 0, stream>>>(k, W2, b2, e, v, vT);
    row_kernel<<<2048, 256, 0, stream>>>(mask, e, attn, P);
    gemm_kernel<<<256, 512, 0, stream>>>(P, vT, out);
}